// Round 6
// baseline (104416.785 us; speedup 1.0000x reference)
//
// LSTM_45337674776685 — R6: batch-partitioned scan, ZERO cross-wg sync.
// R5 lesson: per-step cross-wg exchange through MALL costs 2-4µs/step no
// matter the protocol. But the batch dim is embarrassingly parallel: sample
// b's recurrence never touches other samples. So: 2 wgs x 16 samples, each
// wg owns the FULL hidden state of its samples; h lives in a double-buffered
// LDS tile; ONE intra-wg barrier per step; no global protocol at all.
// Wave w owns h-cols [w*16,w*16+16) for ALL 4 gates -> i,f,g,o of a (s,j)
// pair are lane-local after MFMA (C/D: row=sample, col=j) -> cell update has
// no exchange. Weights register-resident bf16 hi/lo; mfma_f32_16x16x32_bf16
// x3 (emulated fp32); A and B packed with the same k-map (k-perm invariant).

#include <hip/hip_runtime.h>
#include <stdint.h>

typedef unsigned short u16;
typedef unsigned int   u32;
typedef unsigned long long u64;

typedef short  bf16x8 __attribute__((ext_vector_type(8)));
typedef float  f32x4  __attribute__((ext_vector_type(4)));

#define DEVI static __device__ __forceinline__

DEVI u16 f2bf(float x) {
  u32 u = __float_as_uint(x);
  u += 0x7FFFu + ((u >> 16) & 1u);
  return (u16)(u >> 16);
}
DEVI float bf2f(u16 h) { return __uint_as_float(((u32)h) << 16); }

DEVI float sig_nr(float x) {           // ~0.5 ulp (heads)
  float d = 1.f + __expf(-x);
  float r = __builtin_amdgcn_rcpf(d);
  return r * (2.f - d * r);
}
DEVI float silu_f(float x) { return x * sig_nr(x); }
DEVI float sig_r(float x) {            // raw rcp, ~2^-22 rel — scan gates
  return __builtin_amdgcn_rcpf(1.f + __expf(-x));
}

// barrier with LDS-ordering only (no vmcnt drain: hist stores stay in flight)
DEVI void wg_barrier() {
  asm volatile("s_waitcnt lgkmcnt(0)" ::: "memory");
  __builtin_amdgcn_s_barrier();
  asm volatile("" ::: "memory");
}

// ---------------------------------------------------------------------------
// prep: W_hh0/1 -> per-wave MFMA B-fragments (16x16x32 layout), biases.
// frag index: [layer][w(16)][gate(4)][kf(8)][plane(2)][lane(64)][4 u32]
//   row = gate*256 + w*16 + (l&15) ; k = kf*32 + (l>>4)*8 + e
// ---------------------------------------------------------------------------
__global__ void k_prep(const float* __restrict__ Whh0, const float* __restrict__ Whh1,
                       const float* __restrict__ bih0, const float* __restrict__ bhh0,
                       const float* __restrict__ bih1, const float* __restrict__ bhh1,
                       u32* __restrict__ wf, float* __restrict__ biasc)
{
  if (blockIdx.x < 256) {
    int g = blockIdx.x * 256 + threadIdx.x;   // [0, 65536)
    int layer = g >> 15;
    int rem = g & 32767;
    int w  = rem >> 11;
    int gt = (rem >> 9) & 3;
    int kf = (rem >> 6) & 7;
    int l  = rem & 63;
    int row = gt * 256 + w * 16 + (l & 15);
    int k0  = kf * 32 + (l >> 4) * 8;
    const float* W = layer ? Whh1 : Whh0;     // (1024, 256) row-major
    float v[8];
    #pragma unroll
    for (int e = 0; e < 8; ++e) v[e] = W[(size_t)row * 256 + k0 + e];
    u32 hid[4], lod[4];
    #pragma unroll
    for (int p = 0; p < 4; ++p) {
      u16 h0 = f2bf(v[2 * p]), h1 = f2bf(v[2 * p + 1]);
      float l0 = v[2 * p] - bf2f(h0), l1 = v[2 * p + 1] - bf2f(h1);
      hid[p] = (u32)h0 | ((u32)h1 << 16);
      lod[p] = (u32)f2bf(l0) | ((u32)f2bf(l1) << 16);
    }
    size_t hoff = (size_t)layer * 262144
                + ((((size_t)(w * 4 + gt) * 8 + kf) * 2 + 0) * 64 + l) * 4;
    *(uint4*)(wf + hoff)       = make_uint4(hid[0], hid[1], hid[2], hid[3]);
    *(uint4*)(wf + hoff + 256) = make_uint4(lod[0], lod[1], lod[2], lod[3]);
  } else {
    int t = threadIdx.x;
    for (int i = t; i < 1024; i += 256) {
      biasc[i]        = bih0[i] + bhh0[i];
      biasc[1024 + i] = bih1[i] + bhh1[i];
    }
  }
}

// ---------------------------------------------------------------------------
// pack x (B,F,S) -> transposed packed u32 (B,S,F): (hi<<16)|lo
// ---------------------------------------------------------------------------
__global__ void k_packx(const float* __restrict__ x, u32* __restrict__ xp)
{
  __shared__ float tile[64][65];
  const int s0 = blockIdx.x * 64;
  const int b  = blockIdx.y;
  const int t  = threadIdx.x;
  {
    int ss = t & 63, fq = t >> 6;
    #pragma unroll
    for (int r = 0; r < 16; ++r) {
      int f = fq * 16 + r;
      tile[f][ss] = x[((size_t)b * 64 + f) * 2048 + s0 + ss];
    }
  }
  __syncthreads();
  {
    int f2 = t & 63, sq = t >> 6;
    #pragma unroll
    for (int r = 0; r < 16; ++r) {
      int s = sq * 16 + r;
      float v = tile[f2][s];
      u16 hi = f2bf(v);
      u16 lo = f2bf(v - bf2f(hi));
      xp[((size_t)b * 2048 + s0 + s) * 64 + f2] = ((u32)hi << 16) | lo;
    }
  }
}

// ---------------------------------------------------------------------------
// transpose P1 (B,S,64) f32 -> predT (B,64,S) f32
// ---------------------------------------------------------------------------
__global__ void k_transP(const float* __restrict__ P, float* __restrict__ PT)
{
  __shared__ float tile[64][65];
  const int s0 = blockIdx.x * 64;
  const int b  = blockIdx.y;
  const int t  = threadIdx.x;
  {
    int f = t & 63, sq = t >> 6;
    #pragma unroll
    for (int r = 0; r < 16; ++r) {
      int s = sq * 16 + r;
      tile[s][f] = P[((size_t)b * 2048 + s0 + s) * 64 + f];
    }
  }
  __syncthreads();
  {
    int s2 = t & 63, fq = t >> 6;
    #pragma unroll
    for (int r = 0; r < 16; ++r) {
      int ff = fq * 16 + r;
      PT[((size_t)b * 64 + ff) * 2048 + s0 + s2] = tile[s2][ff];
    }
  }
}

// ---------------------------------------------------------------------------
// generic fp32 TN GEMM. UA: A is packed u32 (hi<<16|lo), value = hi + lo.
// MODE 0: +bias ; 1: silu(+bias) ; 2: res + silu(+bias)
// ---------------------------------------------------------------------------
template<int BM, int BN, int TM, int TN, int MODE, int UA>
__global__ __launch_bounds__(256) void k_gemm(
    const float* __restrict__ Af,
    const u32* __restrict__ Ap,
    const float* __restrict__ Bw,
    const float* __restrict__ bias,
    const float* __restrict__ res,
    float* __restrict__ C,
    int K, int lda,
    long a_zrows, long a_row0, long c_zrows, int ldc)
{
  constexpr int BK = 32;
  __shared__ float As[BK][BM + 4];
  __shared__ float Bs[BK][BN + 4];
  const int t  = threadIdx.x;
  const int tx = t & 15, ty = t >> 4;
  const int mb = blockIdx.x * BM, nb = blockIdx.y * BN;
  const long za = (long)blockIdx.z * a_zrows + a_row0 + mb;
  const long zc = (long)blockIdx.z * c_zrows + mb;

  float acc[TM][TN];
  #pragma unroll
  for (int i = 0; i < TM; ++i)
    #pragma unroll
    for (int jn = 0; jn < TN; ++jn) acc[i][jn] = 0.f;

  for (int k0 = 0; k0 < K; k0 += BK) {
    #pragma unroll
    for (int it = 0; it < BM * 8 / 256; ++it) {
      int idx = it * 256 + t;
      int row = idx >> 3, c4 = idx & 7;
      long ar = za + row;
      float v0, v1, v2, v3;
      if (UA) {
        uint4 qv = *(const uint4*)(Ap + (size_t)ar * lda + k0 + c4 * 4);
        v0 = bf2f((u16)(qv.x >> 16)) + bf2f((u16)(qv.x & 0xFFFFu));
        v1 = bf2f((u16)(qv.y >> 16)) + bf2f((u16)(qv.y & 0xFFFFu));
        v2 = bf2f((u16)(qv.z >> 16)) + bf2f((u16)(qv.z & 0xFFFFu));
        v3 = bf2f((u16)(qv.w >> 16)) + bf2f((u16)(qv.w & 0xFFFFu));
      } else {
        float4 f4 = *(const float4*)(Af + (size_t)ar * lda + k0 + c4 * 4);
        v0 = f4.x; v1 = f4.y; v2 = f4.z; v3 = f4.w;
      }
      As[c4 * 4 + 0][row] = v0;
      As[c4 * 4 + 1][row] = v1;
      As[c4 * 4 + 2][row] = v2;
      As[c4 * 4 + 3][row] = v3;
    }
    #pragma unroll
    for (int it = 0; it < BN * 8 / 256; ++it) {
      int idx = it * 256 + t;
      int row = idx >> 3, c4 = idx & 7;
      float4 f4 = *(const float4*)(Bw + (size_t)(nb + row) * K + k0 + c4 * 4);
      Bs[c4 * 4 + 0][row] = f4.x;
      Bs[c4 * 4 + 1][row] = f4.y;
      Bs[c4 * 4 + 2][row] = f4.z;
      Bs[c4 * 4 + 3][row] = f4.w;
    }
    __syncthreads();
    #pragma unroll
    for (int kk = 0; kk < BK; ++kk) {
      float av[TM], bv[TN];
      {
        float4 t0 = *(const float4*)&As[kk][ty * TM];
        av[0] = t0.x; av[1] = t0.y; av[2] = t0.z; av[3] = t0.w;
        if (TM == 8) {
          float4 t1 = *(const float4*)&As[kk][ty * TM + 4];
          av[4] = t1.x; av[5] = t1.y; av[6] = t1.z; av[7] = t1.w;
        }
      }
      {
        float4 t0 = *(const float4*)&Bs[kk][tx * TN];
        bv[0] = t0.x; bv[1] = t0.y; bv[2] = t0.z; bv[3] = t0.w;
        if (TN == 8) {
          float4 t1 = *(const float4*)&Bs[kk][tx * TN + 4];
          bv[4] = t1.x; bv[5] = t1.y; bv[6] = t1.z; bv[7] = t1.w;
        }
      }
      #pragma unroll
      for (int i = 0; i < TM; ++i)
        #pragma unroll
        for (int jn = 0; jn < TN; ++jn)
          acc[i][jn] = fmaf(av[i], bv[jn], acc[i][jn]);
    }
    __syncthreads();
  }
  #pragma unroll
  for (int i = 0; i < TM; ++i) {
    long crow = zc + ty * TM + i;
    float* cp = C + (size_t)crow * ldc + nb + tx * TN;
    const float* rp = res + (size_t)crow * ldc + nb + tx * TN;
    #pragma unroll
    for (int jn = 0; jn < TN; ++jn) {
      float v = acc[i][jn] + bias[nb + tx * TN + jn];
      if (MODE == 1) v = silu_f(v);
      else if (MODE == 2) v = rp[jn] + silu_f(v);
      cp[jn] = v;
    }
  }
}

// ---------------------------------------------------------------------------
// batch-partitioned LSTM scan: grid=2 wgs x 1024 threads (16 waves).
// wg owns samples [wg*16, wg*16+16). Wave w owns h-cols [w*16, w*16+16) for
// all 4 gates. h double-buffered in LDS (u32 hi|lo, row pad 260). One barrier
// per step. c carried in registers (cbuf at chunk bounds); h(t0-1) from hist.
// ---------------------------------------------------------------------------
__global__ __launch_bounds__(1024) void k_scan(
    const u32* __restrict__ wf,            // layer-offset fragments
    const float* __restrict__ xg,          // [B][cs][1024]
    float* __restrict__ cbuf,              // [32][256] f32
    u32* __restrict__ histp,               // [B][2048][256] packed
    int t0, int t1, int cs)
{
  const int tid = threadIdx.x;
  const int w   = tid >> 6;                // wave 0..15
  const int l   = tid & 63;
  const int jj  = l & 15;
  const int kg  = l >> 4;                  // 0..3
  const int j   = w * 16 + jj;             // h col 0..255
  const int b0  = blockIdx.x * 16;         // first sample of this wg

  // weights: [gate][kf] hi/lo fragments
  bf16x8 wh[4][8], wl[4][8];
  #pragma unroll
  for (int g = 0; g < 4; ++g)
    #pragma unroll
    for (int kf = 0; kf < 8; ++kf) {
      const u32* p = wf + ((((size_t)(w * 4 + g) * 8 + kf) * 2) * 64 + l) * 4;
      union { uint4 u; bf16x8 v; } ua, ub;
      ua.u = *(const uint4*)p;
      ub.u = *(const uint4*)(p + 256);
      wh[g][kf] = ua.v; wl[g][kf] = ub.v;
    }

  __shared__ u32 hld[2][16][260];          // [buf][sample][col] packed h

  // init h(t0-1) and c
  {
    int s = tid >> 6, c0 = (tid & 63) * 4;
    if (t0 == 0) {
      *(uint4*)&hld[0][s][c0] = make_uint4(0, 0, 0, 0);
    } else {
      *(uint4*)&hld[t0 & 1][s][c0] =
          *(const uint4*)(histp + ((size_t)(b0 + s) * 2048 + (t0 - 1)) * 256 + c0);
    }
  }
  float c4[4] = {0.f, 0.f, 0.f, 0.f};
  if (t0 > 0) {
    #pragma unroll
    for (int r = 0; r < 4; ++r)
      c4[r] = cbuf[(size_t)(b0 + kg * 4 + r) * 256 + j];
  }
  __syncthreads();

  const int sa = l & 15;                   // A-fragment row (sample)
  const int k8 = kg * 8;                   // A/B k sub-block

  for (int t = t0; t < t1; ++t) {
    const int rb = t & 1, ts = t - t0;

    // xg for this step (consumed in act; MFMA phase hides the latency)
    float xv[4][4];
    #pragma unroll
    for (int g = 0; g < 4; ++g)
      #pragma unroll
      for (int r = 0; r < 4; ++r)
        xv[g][r] = __builtin_nontemporal_load(
            xg + ((size_t)(b0 + kg * 4 + r) * cs + ts) * 1024 + g * 256 + j);

    // h @ W_hh via 96 MFMAs (bf16x3)
    f32x4 a1[4] = {}, a2[4] = {};
    #pragma unroll
    for (int kf = 0; kf < 8; ++kf) {
      const u32* ap = &hld[rb][sa][kf * 32 + k8];
      uint4 q0 = *(const uint4*)ap;
      uint4 q1 = *(const uint4*)(ap + 4);
      union { uint4 u; bf16x8 v; } ua, ub;
      ua.u = make_uint4(__builtin_amdgcn_perm(q0.y, q0.x, 0x07060302u),
                        __builtin_amdgcn_perm(q0.w, q0.z, 0x07060302u),
                        __builtin_amdgcn_perm(q1.y, q1.x, 0x07060302u),
                        __builtin_amdgcn_perm(q1.w, q1.z, 0x07060302u));
      ub.u = make_uint4(__builtin_amdgcn_perm(q0.y, q0.x, 0x05040100u),
                        __builtin_amdgcn_perm(q0.w, q0.z, 0x05040100u),
                        __builtin_amdgcn_perm(q1.y, q1.x, 0x05040100u),
                        __builtin_amdgcn_perm(q1.w, q1.z, 0x05040100u));
      #pragma unroll
      for (int g = 0; g < 4; ++g) {
        a1[g] = __builtin_amdgcn_mfma_f32_16x16x32_bf16(ua.v, wh[g][kf], a1[g], 0, 0, 0);
        a1[g] = __builtin_amdgcn_mfma_f32_16x16x32_bf16(ub.v, wh[g][kf], a1[g], 0, 0, 0);
        a2[g] = __builtin_amdgcn_mfma_f32_16x16x32_bf16(ua.v, wl[g][kf], a2[g], 0, 0, 0);
      }
    }

    // cell update: i,f,g,o are lane-local (row=sample=kg*4+r, col=j)
    const int wb = rb ^ 1;
    #pragma unroll
    for (int r = 0; r < 4; ++r) {
      float pi = a1[0][r] + a2[0][r] + xv[0][r];
      float pf = a1[1][r] + a2[1][r] + xv[1][r];
      float pg = a1[2][r] + a2[2][r] + xv[2][r];
      float po = a1[3][r] + a2[3][r] + xv[3][r];
      float iv = sig_r(pi), fv = sig_r(pf), ov = sig_r(po);
      float gv = 2.f * sig_r(2.f * pg) - 1.f;
      float cn = fmaf(fv, c4[r], iv * gv);
      c4[r] = cn;
      float hv = ov * (2.f * sig_r(2.f * cn) - 1.f);
      u16 sh = f2bf(hv);
      u16 sl = f2bf(hv - bf2f(sh));
      u32 hw = ((u32)sh << 16) | sl;
      int s = kg * 4 + r;
      hld[wb][s][j] = hw;
      __builtin_nontemporal_store(hw,
          histp + ((size_t)(b0 + s) * 2048 + t) * 256 + j);
    }
    wg_barrier();
  }

  #pragma unroll
  for (int r = 0; r < 4; ++r)
    cbuf[(size_t)(b0 + kg * 4 + r) * 256 + j] = c4[r];
}

// ---------------------------------------------------------------------------
// softmax over rows of 2048
// ---------------------------------------------------------------------------
__global__ __launch_bounds__(256) void k_softmax(const float* __restrict__ X,
                                                 float* __restrict__ O)
{
  __shared__ float red[256];
  const int t = threadIdx.x;
  const size_t row = blockIdx.x;
  const float* xr = X + row * 2048;
  float v[8];
  {
    float4 va = *(const float4*)(xr + t * 8);
    float4 vb = *(const float4*)(xr + t * 8 + 4);
    v[0]=va.x; v[1]=va.y; v[2]=va.z; v[3]=va.w;
    v[4]=vb.x; v[5]=vb.y; v[6]=vb.z; v[7]=vb.w;
  }
  float m = v[0];
  #pragma unroll
  for (int i = 1; i < 8; ++i) m = fmaxf(m, v[i]);
  red[t] = m; __syncthreads();
  for (int s = 128; s > 0; s >>= 1) {
    if (t < s) red[t] = fmaxf(red[t], red[t + s]);
    __syncthreads();
  }
  m = red[0];
  __syncthreads();
  float sum = 0.f;
  #pragma unroll
  for (int i = 0; i < 8; ++i) { v[i] = __expf(v[i] - m); sum += v[i]; }
  red[t] = sum; __syncthreads();
  for (int s = 128; s > 0; s >>= 1) {
    if (t < s) red[t] += red[t + s];
    __syncthreads();
  }
  const float inv = 1.f / red[0];
  float* op = O + row * 2048 + t * 8;
  float4 oa = { v[0]*inv, v[1]*inv, v[2]*inv, v[3]*inv };
  float4 ob = { v[4]*inv, v[5]*inv, v[6]*inv, v[7]*inv };
  *(float4*)op = oa;
  *(float4*)(op + 4) = ob;
}

// ---------------------------------------------------------------------------
extern "C" void kernel_launch(void* const* d_in, const int* in_sizes, int n_in,
                              void* d_out, int out_size, void* d_ws, size_t ws_size,
                              hipStream_t stream)
{
  const float* x    = (const float*)d_in[0];
  const float* Wih0 = (const float*)d_in[1];
  const float* Whh0 = (const float*)d_in[2];
  const float* bih0 = (const float*)d_in[3];
  const float* bhh0 = (const float*)d_in[4];
  const float* Wih1 = (const float*)d_in[5];
  const float* Whh1 = (const float*)d_in[6];
  const float* bih1 = (const float*)d_in[7];
  const float* bhh1 = (const float*)d_in[8];
  const float* W1   = (const float*)d_in[9];
  const float* b1   = (const float*)d_in[10];
  const float* W1b  = (const float*)d_in[11];
  const float* b1b  = (const float*)d_in[12];
  const float* W2   = (const float*)d_in[13];
  const float* b2   = (const float*)d_in[14];
  const float* W2b  = (const float*)d_in[15];
  const float* b2b  = (const float*)d_in[16];
  (void)in_sizes; (void)n_in;

  const size_t HP  = (size_t)32 * 2048 * 256 * 4;   // packed history: 64MB
  const size_t XT  = (size_t)32 * 2048 * 64 * 4;    // packed x: 16.8MB
  const size_t WF  = (size_t)2 * 262144 * 4;        // 2MB fragments

  auto need = [&](int c) -> size_t {
    return (size_t)32 * c * 1024 * 4 + 2 * HP + XT + WF + (4u << 20);
  };
  int cs = 2048;
  while (cs > 512 && need(cs) > ws_size) cs >>= 1;
  if (need(cs) > ws_size) {
    hipMemsetAsync(d_out, 0x7F, (size_t)out_size * 4, stream);
    return;
  }

  char* w = (char*)d_ws;
  size_t off = 0;
  auto take = [&](size_t bytes) {
    size_t r = off;
    off = (off + bytes + 255) & ~(size_t)255;
    return r;
  };
  size_t o_xg   = take((size_t)32 * cs * 1024 * 4);
  size_t o_h0p  = take(HP);
  size_t o_h1p  = take(HP);
  size_t o_xp   = take(XT);
  size_t o_wf   = take(WF);
  size_t o_bias = take(8192);
  size_t o_cbuf = take(32 * 256 * 4);

  float* xg    = (float*)(w + o_xg);
  u32*   h0p   = (u32*)(w + o_h0p);
  u32*   h1p   = (u32*)(w + o_h1p);
  u32*   xp    = (u32*)(w + o_xp);
  u32*   wf    = (u32*)(w + o_wf);
  float* biasc = (float*)(w + o_bias);
  float* cbuf  = (float*)(w + o_cbuf);
  // overlays (dead regions at head time)
  const size_t PB = 17825792;   // 17MB slot
  float* P0    = (float*)(w + o_h0p);
  float* P1    = (float*)(w + o_h0p + PB);
  float* predT = (float*)(w + o_h0p + 2 * PB);
  float* out1  = (float*)(w + o_xg);
  float* out2  = (float*)(w + o_xg + PB);

  k_prep<<<257, 256, 0, stream>>>(Whh0, Whh1, bih0, bhh0, bih1, bhh1,
                                  wf, biasc);
  k_packx<<<dim3(32, 32), 256, 0, stream>>>(x, xp);

  const int Q = 2048 / cs;
  for (int qq = 0; qq < Q; ++qq) {
    k_gemm<128, 128, 8, 8, 0, 1><<<dim3(cs / 128, 8, 32), 256, 0, stream>>>(
        nullptr, xp, Wih0, biasc, xg, xg,
        64, 64, 2048, (long)qq * cs, cs, 1024);
    k_scan<<<2, 1024, 0, stream>>>(wf, xg, cbuf, h0p,
                                   qq * cs, (qq + 1) * cs, cs);
  }
  for (int qq = 0; qq < Q; ++qq) {
    k_gemm<128, 128, 8, 8, 0, 1><<<dim3(cs / 128, 8, 32), 256, 0, stream>>>(
        nullptr, h0p, Wih1, biasc + 1024, xg, xg,
        256, 256, 2048, (long)qq * cs, cs, 1024);
    k_scan<<<2, 1024, 0, stream>>>(wf + 262144, xg, cbuf, h1p,
                                   qq * cs, (qq + 1) * cs, cs);
  }
  // heads
  k_gemm<128, 64, 8, 4, 1, 1><<<dim3(512, 1, 1), 256, 0, stream>>>(
      nullptr, h1p, W1, b1, P0, P0, 256, 256, 0, 0, 0, 64);
  k_gemm<128, 64, 8, 4, 2, 0><<<dim3(512, 1, 1), 256, 0, stream>>>(
      P0, nullptr, W1b, b1b, P0, P1, 64, 64, 0, 0, 0, 64);
  k_transP<<<dim3(32, 32), 256, 0, stream>>>(P1, predT);
  k_gemm<128, 128, 8, 8, 0, 0><<<dim3(16, 16, 1), 256, 0, stream>>>(
      predT, nullptr, W2, b2, out1, out1, 2048, 2048, 0, 0, 0, 2048);
  k_gemm<128, 128, 8, 8, 2, 0><<<dim3(16, 16, 1), 256, 0, stream>>>(
      out1, nullptr, W2b, b2b, out1, out2, 2048, 2048, 0, 0, 0, 2048);
  k_softmax<<<2048, 256, 0, stream>>>(out2, (float*)d_out);
}

// Round 7
// 21680.817 us; speedup vs baseline: 4.8161x; 4.8161x over previous
//
// LSTM_45337674776685 — R7: 4-CU groups, same-XCD L2 exchange, no barriers.
// R6 lesson: 1 layer's bf16-hi/lo W_hh (1MB) can't fit one CU's 512KB RF ->
// spills -> L2-BW-bound (6µs/step). R7: 2 groups x 16 samples, 4 CUs/group,
// 8 wgs claimed onto ONE XCD. Per wg: 4 waves (1/SIMD, 512-VGPR budget),
// wave owns a 16-col slice x 4 gates (256 VGPR of weights, verified R6
// 16x16x32 fragment maps). Exchange via tag-in-data u32 (hi16|lo14|tag2) in
// a 4-slot ring in global (XCD L2): producers plain-store (writethrough),
// consumers nontemporal-load (no L1 allocate -> re-probes L2), escalate to
// agent/sc1 atomics after 4 attempts (proven R5 path as floor). No flags,
// no vmcnt on critical path, no __syncthreads in the step loop.

#include <hip/hip_runtime.h>
#include <stdint.h>

typedef unsigned short u16;
typedef unsigned int   u32;
typedef unsigned long long u64;

typedef short  bf16x8 __attribute__((ext_vector_type(8)));
typedef float  f32x4  __attribute__((ext_vector_type(4)));

#define DEVI static __device__ __forceinline__

DEVI u16 f2bf(float x) {
  u32 u = __float_as_uint(x);
  u += 0x7FFFu + ((u >> 16) & 1u);
  return (u16)(u >> 16);
}
DEVI float bf2f(u16 h) { return __uint_as_float(((u32)h) << 16); }

DEVI float sig_nr(float x) {           // ~0.5 ulp (heads)
  float d = 1.f + __expf(-x);
  float r = __builtin_amdgcn_rcpf(d);
  return r * (2.f - d * r);
}
DEVI float silu_f(float x) { return x * sig_nr(x); }
DEVI float sig_r(float x) {            // raw rcp — scan gates (R6-verified)
  return __builtin_amdgcn_rcpf(1.f + __expf(-x));
}

// ---------------------------------------------------------------------------
// prep: blocks 0-255 weights -> 16x16x32 B-frags (R6-verified layout);
// blocks 256-511 hbuf tag init (=3); block 512 biases + claim areas.
// frag: [layer][cs16(16)][gate(4)][kf(8)][plane(2)][lane(64)][4 u32]
//   row = gate*256 + cs16*16 + (l&15) ; k = kf*32 + (l>>4)*8 + e
// ---------------------------------------------------------------------------
__global__ void k_prep(const float* __restrict__ Whh0, const float* __restrict__ Whh1,
                       const float* __restrict__ bih0, const float* __restrict__ bhh0,
                       const float* __restrict__ bih1, const float* __restrict__ bhh1,
                       u32* __restrict__ wf, float* __restrict__ biasc,
                       u32* __restrict__ hbuf, u32* __restrict__ claims)
{
  if (blockIdx.x < 256) {
    int g = blockIdx.x * 256 + threadIdx.x;   // [0, 65536)
    int layer = g >> 15;
    int rem = g & 32767;
    int w  = rem >> 11;          // cs16
    int gt = (rem >> 9) & 3;
    int kf = (rem >> 6) & 7;
    int l  = rem & 63;
    int row = gt * 256 + w * 16 + (l & 15);
    int k0  = kf * 32 + (l >> 4) * 8;
    const float* W = layer ? Whh1 : Whh0;     // (1024, 256) row-major
    float v[8];
    #pragma unroll
    for (int e = 0; e < 8; ++e) v[e] = W[(size_t)row * 256 + k0 + e];
    u32 hid[4], lod[4];
    #pragma unroll
    for (int p = 0; p < 4; ++p) {
      u16 h0 = f2bf(v[2 * p]), h1 = f2bf(v[2 * p + 1]);
      float l0 = v[2 * p] - bf2f(h0), l1 = v[2 * p + 1] - bf2f(h1);
      hid[p] = (u32)h0 | ((u32)h1 << 16);
      lod[p] = (u32)f2bf(l0) | ((u32)f2bf(l1) << 16);
    }
    size_t hoff = (size_t)layer * 262144
                + ((((size_t)(w * 4 + gt) * 8 + kf) * 2 + 0) * 64 + l) * 4;
    *(uint4*)(wf + hoff)       = make_uint4(hid[0], hid[1], hid[2], hid[3]);
    *(uint4*)(wf + hoff + 256) = make_uint4(lod[0], lod[1], lod[2], lod[3]);
  } else if (blockIdx.x < 512) {
    // hbuf: 2 layers x 2 groups x 4 slots x 16 x 256 = 65536 u32; tag init 3
    // (expected tags start at 0 and spread<=2 steps -> 3 never aliases).
    int idx = (blockIdx.x - 256) * 256 + threadIdx.x;
    hbuf[idx] = 3u;
  } else {
    int t = threadIdx.x;
    // 8 claim areas x 32 u32: counts[16]=0, winner[16]=0xFFFFFFFF
    claims[t] = ((t & 31) == 16) ? 0xFFFFFFFFu : 0u;
    for (int i = t; i < 1024; i += 256) {
      biasc[i]        = bih0[i] + bhh0[i];
      biasc[1024 + i] = bih1[i] + bhh1[i];
    }
  }
}

// ---------------------------------------------------------------------------
// pack x (B,F,S) -> transposed packed u32 (B,S,F): (hi<<16)|lo
// ---------------------------------------------------------------------------
__global__ void k_packx(const float* __restrict__ x, u32* __restrict__ xp)
{
  __shared__ float tile[64][65];
  const int s0 = blockIdx.x * 64;
  const int b  = blockIdx.y;
  const int t  = threadIdx.x;
  {
    int ss = t & 63, fq = t >> 6;
    #pragma unroll
    for (int r = 0; r < 16; ++r) {
      int f = fq * 16 + r;
      tile[f][ss] = x[((size_t)b * 64 + f) * 2048 + s0 + ss];
    }
  }
  __syncthreads();
  {
    int f2 = t & 63, sq = t >> 6;
    #pragma unroll
    for (int r = 0; r < 16; ++r) {
      int s = sq * 16 + r;
      float v = tile[f2][s];
      u16 hi = f2bf(v);
      u16 lo = f2bf(v - bf2f(hi));
      xp[((size_t)b * 2048 + s0 + s) * 64 + f2] = ((u32)hi << 16) | lo;
    }
  }
}

// ---------------------------------------------------------------------------
// transpose P1 (B,S,64) f32 -> predT (B,64,S) f32
// ---------------------------------------------------------------------------
__global__ void k_transP(const float* __restrict__ P, float* __restrict__ PT)
{
  __shared__ float tile[64][65];
  const int s0 = blockIdx.x * 64;
  const int b  = blockIdx.y;
  const int t  = threadIdx.x;
  {
    int f = t & 63, sq = t >> 6;
    #pragma unroll
    for (int r = 0; r < 16; ++r) {
      int s = sq * 16 + r;
      tile[s][f] = P[((size_t)b * 2048 + s0 + s) * 64 + f];
    }
  }
  __syncthreads();
  {
    int s2 = t & 63, fq = t >> 6;
    #pragma unroll
    for (int r = 0; r < 16; ++r) {
      int ff = fq * 16 + r;
      PT[((size_t)b * 64 + ff) * 2048 + s0 + s2] = tile[s2][ff];
    }
  }
}

// ---------------------------------------------------------------------------
// generic fp32 TN GEMM. UA: A is packed u32 (hi<<16|lo), value = hi + lo.
// MODE 0: +bias ; 1: silu(+bias) ; 2: res + silu(+bias)
// ---------------------------------------------------------------------------
template<int BM, int BN, int TM, int TN, int MODE, int UA>
__global__ __launch_bounds__(256) void k_gemm(
    const float* __restrict__ Af,
    const u32* __restrict__ Ap,
    const float* __restrict__ Bw,
    const float* __restrict__ bias,
    const float* __restrict__ res,
    float* __restrict__ C,
    int K, int lda,
    long a_zrows, long a_row0, long c_zrows, int ldc)
{
  constexpr int BK = 32;
  __shared__ float As[BK][BM + 4];
  __shared__ float Bs[BK][BN + 4];
  const int t  = threadIdx.x;
  const int tx = t & 15, ty = t >> 4;
  const int mb = blockIdx.x * BM, nb = blockIdx.y * BN;
  const long za = (long)blockIdx.z * a_zrows + a_row0 + mb;
  const long zc = (long)blockIdx.z * c_zrows + mb;

  float acc[TM][TN];
  #pragma unroll
  for (int i = 0; i < TM; ++i)
    #pragma unroll
    for (int jn = 0; jn < TN; ++jn) acc[i][jn] = 0.f;

  for (int k0 = 0; k0 < K; k0 += BK) {
    #pragma unroll
    for (int it = 0; it < BM * 8 / 256; ++it) {
      int idx = it * 256 + t;
      int row = idx >> 3, c4 = idx & 7;
      long ar = za + row;
      float v0, v1, v2, v3;
      if (UA) {
        uint4 qv = *(const uint4*)(Ap + (size_t)ar * lda + k0 + c4 * 4);
        v0 = bf2f((u16)(qv.x >> 16)) + bf2f((u16)(qv.x & 0xFFFFu));
        v1 = bf2f((u16)(qv.y >> 16)) + bf2f((u16)(qv.y & 0xFFFFu));
        v2 = bf2f((u16)(qv.z >> 16)) + bf2f((u16)(qv.z & 0xFFFFu));
        v3 = bf2f((u16)(qv.w >> 16)) + bf2f((u16)(qv.w & 0xFFFFu));
      } else {
        float4 f4 = *(const float4*)(Af + (size_t)ar * lda + k0 + c4 * 4);
        v0 = f4.x; v1 = f4.y; v2 = f4.z; v3 = f4.w;
      }
      As[c4 * 4 + 0][row] = v0;
      As[c4 * 4 + 1][row] = v1;
      As[c4 * 4 + 2][row] = v2;
      As[c4 * 4 + 3][row] = v3;
    }
    #pragma unroll
    for (int it = 0; it < BN * 8 / 256; ++it) {
      int idx = it * 256 + t;
      int row = idx >> 3, c4 = idx & 7;
      float4 f4 = *(const float4*)(Bw + (size_t)(nb + row) * K + k0 + c4 * 4);
      Bs[c4 * 4 + 0][row] = f4.x;
      Bs[c4 * 4 + 1][row] = f4.y;
      Bs[c4 * 4 + 2][row] = f4.z;
      Bs[c4 * 4 + 3][row] = f4.w;
    }
    __syncthreads();
    #pragma unroll
    for (int kk = 0; kk < BK; ++kk) {
      float av[TM], bv[TN];
      {
        float4 t0 = *(const float4*)&As[kk][ty * TM];
        av[0] = t0.x; av[1] = t0.y; av[2] = t0.z; av[3] = t0.w;
        if (TM == 8) {
          float4 t1 = *(const float4*)&As[kk][ty * TM + 4];
          av[4] = t1.x; av[5] = t1.y; av[6] = t1.z; av[7] = t1.w;
        }
      }
      {
        float4 t0 = *(const float4*)&Bs[kk][tx * TN];
        bv[0] = t0.x; bv[1] = t0.y; bv[2] = t0.z; bv[3] = t0.w;
        if (TN == 8) {
          float4 t1 = *(const float4*)&Bs[kk][tx * TN + 4];
          bv[4] = t1.x; bv[5] = t1.y; bv[6] = t1.z; bv[7] = t1.w;
        }
      }
      #pragma unroll
      for (int i = 0; i < TM; ++i)
        #pragma unroll
        for (int jn = 0; jn < TN; ++jn)
          acc[i][jn] = fmaf(av[i], bv[jn], acc[i][jn]);
    }
    __syncthreads();
  }
  #pragma unroll
  for (int i = 0; i < TM; ++i) {
    long crow = zc + ty * TM + i;
    float* cp = C + (size_t)crow * ldc + nb + tx * TN;
    const float* rp = res + (size_t)crow * ldc + nb + tx * TN;
    #pragma unroll
    for (int jn = 0; jn < TN; ++jn) {
      float v = acc[i][jn] + bias[nb + tx * TN + jn];
      if (MODE == 1) v = silu_f(v);
      else if (MODE == 2) v = rp[jn] + silu_f(v);
      cp[jn] = v;
    }
  }
}

// ---------------------------------------------------------------------------
// LSTM scan: 256 wgs x 256 thr launched; 8 self-claim one XCD. wg w: group
// g=w>>2 (16 samples), quadrant qd=w&3. Wave v -> col-slice cs16=qd*4+v
// (16 cols x 4 gates, weights 256 VGPR). hbuf[group][slot4][16][256] u32 ring
// (hi16|lo14|tag2). Consumers nt-load + tag-verify (sc1 after 4 tries).
// Producers plain-store. No barriers/flags/vmcnt in the loop.
// ---------------------------------------------------------------------------
__global__ __launch_bounds__(256, 1) void k_scan(
    const u32* __restrict__ wf,            // this layer's fragments
    const float* __restrict__ xg,          // [32][cs][1024]
    u32* __restrict__ hbuf,                // this layer: [2][4][16][256]
    float* __restrict__ cbuf,              // [32][256]
    u32* __restrict__ histp,               // [32][2048][256]
    u32* __restrict__ claim,               // [32]
    int t0, int t1, int cs)
{
  __shared__ int s_role;
  if (threadIdx.x == 0) {
    u32 xcc;
    asm volatile("s_getreg_b32 %0, hwreg(20, 0, 4)" : "=s"(xcc));
    xcc &= 15u;
    u32 role = __hip_atomic_fetch_add(&claim[xcc], 1u,
                                      __ATOMIC_RELAXED, __HIP_MEMORY_SCOPE_AGENT);
    if (role == 7u) {
      u32 exp = 0xFFFFFFFFu;
      __hip_atomic_compare_exchange_strong(&claim[16], &exp, xcc,
          __ATOMIC_RELAXED, __ATOMIC_RELAXED, __HIP_MEMORY_SCOPE_AGENT);
    }
    u32 wv; int guard = 0;
    do {
      wv = __hip_atomic_load(&claim[16], __ATOMIC_RELAXED, __HIP_MEMORY_SCOPE_AGENT);
    } while (wv == 0xFFFFFFFFu && ++guard < (1 << 20));
    s_role = (wv == xcc && role < 8u) ? (int)role : -1;
  }
  __syncthreads();
  const int w = s_role;
  if (w < 0) return;

  const int g    = w >> 2;
  const int qd   = w & 3;
  const int v    = threadIdx.x >> 6;
  const int l    = threadIdx.x & 63;
  const int cs16 = qd * 4 + v;
  const int jj   = l & 15;
  const int kg   = l >> 4;                 // 0..3
  const int j    = cs16 * 16 + jj;         // col 0..255
  const int b0   = g * 16;

  // weights: [gate][kf] hi/lo fragments for this col-slice
  bf16x8 wh[4][8], wl[4][8];
  #pragma unroll
  for (int gt = 0; gt < 4; ++gt)
    #pragma unroll
    for (int kf = 0; kf < 8; ++kf) {
      const u32* p = wf + ((((size_t)(cs16 * 4 + gt) * 8 + kf) * 2) * 64 + l) * 4;
      union { uint4 u; bf16x8 vv; } ua, ub;
      ua.u = *(const uint4*)p;
      ub.u = *(const uint4*)(p + 256);
      wh[gt][kf] = ua.vv; wl[gt][kf] = ub.vv;
    }

  float c4[4] = {0.f, 0.f, 0.f, 0.f};
  if (t0 > 0) {
    #pragma unroll
    for (int r = 0; r < 4; ++r)
      c4[r] = cbuf[(size_t)(b0 + kg * 4 + r) * 256 + j];
  }

  u32* hb = hbuf + (size_t)g * 16384;      // [4][16][256]
  const u32 arow = (u32)(l & 15) * 256 + (u32)kg * 8;

  for (int t = t0; t < t1; ++t) {
    const int ts = t - t0;

    // xg (nt, issued before the exchange wait)
    float xv[4][4];
    #pragma unroll
    for (int gt = 0; gt < 4; ++gt)
      #pragma unroll
      for (int r = 0; r < 4; ++r)
        xv[gt][r] = __builtin_nontemporal_load(
            xg + ((size_t)(b0 + kg * 4 + r) * cs + ts) * 1024 + gt * 256 + j);

    f32x4 a1[4] = {}, a2[4] = {};
    if (t > 0) {
      const u32* ap = hb + ((u32)(t - 1) & 3u) * 4096 + arow;
      const u32 et = ((u32)(t - 1) >> 2) & 3u;
      u64 d[32];
      int att = 0;
      while (true) {
        if (att < 4) {
          #pragma unroll
          for (int kf = 0; kf < 8; ++kf)
            #pragma unroll
            for (int m = 0; m < 4; ++m)
              d[kf * 4 + m] = __builtin_nontemporal_load(
                  (const u64*)(ap + kf * 32 + 2 * m));
        } else {
          #pragma unroll
          for (int kf = 0; kf < 8; ++kf)
            #pragma unroll
            for (int m = 0; m < 4; ++m)
              d[kf * 4 + m] = __hip_atomic_load(
                  (const u64*)(ap + kf * 32 + 2 * m),
                  __ATOMIC_RELAXED, __HIP_MEMORY_SCOPE_AGENT);
        }
        u32 orv = 0;
        #pragma unroll
        for (int i = 0; i < 32; ++i)
          orv |= ((u32)d[i] ^ et) | ((u32)(d[i] >> 32) ^ et);
        if (__all((int)((orv & 3u) == 0u))) break;
        if (++att > 4096) break;
        asm volatile("" ::: "memory");     // force reload in the retry loop
      }
      // unpack + 96 MFMAs (R5-verified perm scheme; R6-verified frag maps)
      #pragma unroll
      for (int kf = 0; kf < 8; ++kf) {
        u32 e0 = (u32)d[kf*4+0], e1 = (u32)(d[kf*4+0] >> 32);
        u32 e2 = (u32)d[kf*4+1], e3 = (u32)(d[kf*4+1] >> 32);
        u32 e4 = (u32)d[kf*4+2], e5 = (u32)(d[kf*4+2] >> 32);
        u32 e6 = (u32)d[kf*4+3], e7 = (u32)(d[kf*4+3] >> 32);
        union { uint4 u; bf16x8 vv; } ua, ub;
        ua.u = make_uint4(__builtin_amdgcn_perm(e1, e0, 0x07060302u),
                          __builtin_amdgcn_perm(e3, e2, 0x07060302u),
                          __builtin_amdgcn_perm(e5, e4, 0x07060302u),
                          __builtin_amdgcn_perm(e7, e6, 0x07060302u));
        ub.u = make_uint4(__builtin_amdgcn_perm(e1, e0, 0x05040100u) & 0xFFFCFFFCu,
                          __builtin_amdgcn_perm(e3, e2, 0x05040100u) & 0xFFFCFFFCu,
                          __builtin_amdgcn_perm(e5, e4, 0x05040100u) & 0xFFFCFFFCu,
                          __builtin_amdgcn_perm(e7, e6, 0x05040100u) & 0xFFFCFFFCu);
        #pragma unroll
        for (int gt = 0; gt < 4; ++gt) {
          a1[gt] = __builtin_amdgcn_mfma_f32_16x16x32_bf16(ua.vv, wh[gt][kf], a1[gt], 0, 0, 0);
          a1[gt] = __builtin_amdgcn_mfma_f32_16x16x32_bf16(ub.vv, wh[gt][kf], a1[gt], 0, 0, 0);
          a2[gt] = __builtin_amdgcn_mfma_f32_16x16x32_bf16(ua.vv, wl[gt][kf], a2[gt], 0, 0, 0);
        }
      }
    }

    // cell update: i,f,g,o lane-local (sample = kg*4+r, col = j)
    u32* dst = hb + ((u32)t & 3u) * 4096;
    const u32 tg = ((u32)t >> 2) & 3u;
    #pragma unroll
    for (int r = 0; r < 4; ++r) {
      float pi = a1[0][r] + a2[0][r] + xv[0][r];
      float pf = a1[1][r] + a2[1][r] + xv[1][r];
      float pg = a1[2][r] + a2[2][r] + xv[2][r];
      float po = a1[3][r] + a2[3][r] + xv[3][r];
      float iv = sig_r(pi), fv = sig_r(pf), ov = sig_r(po);
      float gv = 2.f * sig_r(2.f * pg) - 1.f;
      float cn = fmaf(fv, c4[r], iv * gv);
      c4[r] = cn;
      float hv = ov * (2.f * sig_r(2.f * cn) - 1.f);
      u16 sh = f2bf(hv);
      u16 sl = f2bf(hv - bf2f(sh));
      int s = kg * 4 + r;
      dst[(size_t)s * 256 + j] = ((u32)sh << 16) | ((u32)sl & 0xFFFCu) | tg;
      __builtin_nontemporal_store(((u32)sh << 16) | (u32)sl,
          histp + ((size_t)(b0 + s) * 2048 + t) * 256 + j);
    }
  }

  #pragma unroll
  for (int r = 0; r < 4; ++r)
    cbuf[(size_t)(b0 + kg * 4 + r) * 256 + j] = c4[r];
}

// ---------------------------------------------------------------------------
// softmax over rows of 2048
// ---------------------------------------------------------------------------
__global__ __launch_bounds__(256) void k_softmax(const float* __restrict__ X,
                                                 float* __restrict__ O)
{
  __shared__ float red[256];
  const int t = threadIdx.x;
  const size_t row = blockIdx.x;
  const float* xr = X + row * 2048;
  float v[8];
  {
    float4 va = *(const float4*)(xr + t * 8);
    float4 vb = *(const float4*)(xr + t * 8 + 4);
    v[0]=va.x; v[1]=va.y; v[2]=va.z; v[3]=va.w;
    v[4]=vb.x; v[5]=vb.y; v[6]=vb.z; v[7]=vb.w;
  }
  float m = v[0];
  #pragma unroll
  for (int i = 1; i < 8; ++i) m = fmaxf(m, v[i]);
  red[t] = m; __syncthreads();
  for (int s = 128; s > 0; s >>= 1) {
    if (t < s) red[t] = fmaxf(red[t], red[t + s]);
    __syncthreads();
  }
  m = red[0];
  __syncthreads();
  float sum = 0.f;
  #pragma unroll
  for (int i = 0; i < 8; ++i) { v[i] = __expf(v[i] - m); sum += v[i]; }
  red[t] = sum; __syncthreads();
  for (int s = 128; s > 0; s >>= 1) {
    if (t < s) red[t] += red[t + s];
    __syncthreads();
  }
  const float inv = 1.f / red[0];
  float* op = O + row * 2048 + t * 8;
  float4 oa = { v[0]*inv, v[1]*inv, v[2]*inv, v[3]*inv };
  float4 ob = { v[4]*inv, v[5]*inv, v[6]*inv, v[7]*inv };
  *(float4*)op = oa;
  *(float4*)(op + 4) = ob;
}

// ---------------------------------------------------------------------------
extern "C" void kernel_launch(void* const* d_in, const int* in_sizes, int n_in,
                              void* d_out, int out_size, void* d_ws, size_t ws_size,
                              hipStream_t stream)
{
  const float* x    = (const float*)d_in[0];
  const float* Wih0 = (const float*)d_in[1];
  const float* Whh0 = (const float*)d_in[2];
  const float* bih0 = (const float*)d_in[3];
  const float* bhh0 = (const float*)d_in[4];
  const float* Wih1 = (const float*)d_in[5];
  const float* Whh1 = (const float*)d_in[6];
  const float* bih1 = (const float*)d_in[7];
  const float* bhh1 = (const float*)d_in[8];
  const float* W1   = (const float*)d_in[9];
  const float* b1   = (const float*)d_in[10];
  const float* W1b  = (const float*)d_in[11];
  const float* b1b  = (const float*)d_in[12];
  const float* W2   = (const float*)d_in[13];
  const float* b2   = (const float*)d_in[14];
  const float* W2b  = (const float*)d_in[15];
  const float* b2b  = (const float*)d_in[16];
  (void)in_sizes; (void)n_in;

  const size_t HP  = (size_t)32 * 2048 * 256 * 4;   // packed history: 64MB
  const size_t XT  = (size_t)32 * 2048 * 64 * 4;    // packed x: 16.8MB
  const size_t WF  = (size_t)2 * 262144 * 4;        // 2MB fragments

  auto need = [&](int c) -> size_t {
    return (size_t)32 * c * 1024 * 4 + 2 * HP + XT + WF + (4u << 20);
  };
  int cs = 2048;
  while (cs > 256 && need(cs) > ws_size) cs >>= 1;
  if (need(cs) > ws_size) {
    hipMemsetAsync(d_out, 0x7F, (size_t)out_size * 4, stream);
    return;
  }

  char* w = (char*)d_ws;
  size_t off = 0;
  auto take = [&](size_t bytes) {
    size_t r = off;
    off = (off + bytes + 255) & ~(size_t)255;
    return r;
  };
  size_t o_xg   = take((size_t)32 * cs * 1024 * 4);
  size_t o_h0p  = take(HP);
  size_t o_h1p  = take(HP);
  size_t o_xp   = take(XT);
  size_t o_wf   = take(WF);
  size_t o_hb   = take(2 * 32768 * 4);   // 2 layers x [2][4][16][256]
  size_t o_bias = take(8192);
  size_t o_cbuf = take(32 * 256 * 4);
  size_t o_clm  = take(8 * 32 * 4);

  float* xg    = (float*)(w + o_xg);
  u32*   h0p   = (u32*)(w + o_h0p);
  u32*   h1p   = (u32*)(w + o_h1p);
  u32*   xp    = (u32*)(w + o_xp);
  u32*   wf    = (u32*)(w + o_wf);
  u32*   hbuf  = (u32*)(w + o_hb);
  float* biasc = (float*)(w + o_bias);
  float* cbuf  = (float*)(w + o_cbuf);
  u32*   clms  = (u32*)(w + o_clm);
  // overlays (dead regions at head time)
  const size_t PB = 17825792;   // 17MB slot
  float* P0    = (float*)(w + o_h0p);
  float* P1    = (float*)(w + o_h0p + PB);
  float* predT = (float*)(w + o_h0p + 2 * PB);
  float* out1  = (float*)(w + o_xg);
  float* out2  = (float*)(w + o_xg + PB);

  k_prep<<<513, 256, 0, stream>>>(Whh0, Whh1, bih0, bhh0, bih1, bhh1,
                                  wf, biasc, hbuf, clms);
  k_packx<<<dim3(32, 32), 256, 0, stream>>>(x, xp);

  const int Q = 2048 / cs;
  int li = 0;
  for (int qq = 0; qq < Q; ++qq) {
    k_gemm<128, 128, 8, 8, 0, 1><<<dim3(cs / 128, 8, 32), 256, 0, stream>>>(
        nullptr, xp, Wih0, biasc, xg, xg,
        64, 64, 2048, (long)qq * cs, cs, 1024);
    k_scan<<<256, 256, 0, stream>>>(wf, xg, hbuf, cbuf, h0p,
                                    clms + (li++) * 32,
                                    qq * cs, (qq + 1) * cs, cs);
  }
  for (int qq = 0; qq < Q; ++qq) {
    k_gemm<128, 128, 8, 8, 0, 1><<<dim3(cs / 128, 8, 32), 256, 0, stream>>>(
        nullptr, h0p, Wih1, biasc + 1024, xg, xg,
        256, 256, 2048, (long)qq * cs, cs, 1024);
    k_scan<<<256, 256, 0, stream>>>(wf + 262144, xg, hbuf + 32768, cbuf, h1p,
                                    clms + (li++) * 32,
                                    qq * cs, (qq + 1) * cs, cs);
  }
  // heads
  k_gemm<128, 64, 8, 4, 1, 1><<<dim3(512, 1, 1), 256, 0, stream>>>(
      nullptr, h1p, W1, b1, P0, P0, 256, 256, 0, 0, 0, 64);
  k_gemm<128, 64, 8, 4, 2, 0><<<dim3(512, 1, 1), 256, 0, stream>>>(
      P0, nullptr, W1b, b1b, P0, P1, 64, 64, 0, 0, 0, 64);
  k_transP<<<dim3(32, 32), 256, 0, stream>>>(P1, predT);
  k_gemm<128, 128, 8, 8, 0, 0><<<dim3(16, 16, 1), 256, 0, stream>>>(
      predT, nullptr, W2, b2, out1, out1, 2048, 2048, 0, 0, 0, 2048);
  k_gemm<128, 128, 8, 8, 2, 0><<<dim3(16, 16, 1), 256, 0, stream>>>(
      out1, nullptr, W2b, b2b, out1, out2, 2048, 2048, 0, 0, 0, 2048);
  k_softmax<<<2048, 256, 0, stream>>>(out2, (float*)d_out);
}